// Round 1
// baseline (10711.258 us; speedup 1.0000x reference)
//
#include <hip/hip_runtime.h>

// Problem constants (fixed by the reference): B=8, C=256, H=W=64, PATCH=3.
constexpr int BATCH = 8;
constexpr int C = 256;
constexpr int H = 64;
constexpr int W = 64;
constexpr int HW = H * W;          // 4096
constexpr int HH = 62, WW = 62;    // valid patch grid
constexpr int NQ = HH * WW;        // 3844 patches per image
constexpr int ITILES = (NQ + 63) / 64;  // 61

// ---------------------------------------------------------------------------
// Kernel 1: per-position reciprocal channel-L2 norm for both feature tensors.
// rnorm layout: [tensor(2)][b(8)][pos(4096)]
// ---------------------------------------------------------------------------
__global__ __launch_bounds__(256) void norm_kernel(const float* __restrict__ f1,
                                                   const float* __restrict__ f2,
                                                   float* __restrict__ rnorm) {
  int by = blockIdx.x;           // b*H + y
  int tensor = blockIdx.y;       // 0 -> f1, 1 -> f2
  const float* f = tensor ? f2 : f1;
  int b = by >> 6, y = by & 63;
  int x = threadIdx.x & 63;
  int cq = threadIdx.x >> 6;     // 0..3
  const float* base = f + ((size_t)b * C) * HW + y * W + x;
  float s = 0.f;
  for (int c = cq; c < C; c += 4) {
    float v = base[(size_t)c * HW];
    s = fmaf(v, v, s);
  }
  __shared__ float sm[4][64];
  sm[cq][x] = s;
  __syncthreads();
  if (threadIdx.x < 64) {
    float t = sm[0][x] + sm[1][x] + sm[2][x] + sm[3][x];
    float nrm = fmaxf(sqrtf(t), 1e-12f);
    rnorm[((size_t)tensor * BATCH + b) * HW + y * W + x] = 1.0f / nrm;
  }
}

// ---------------------------------------------------------------------------
// Kernel 2: implicit-patch correlation GEMM + running row argmax.
// Block: 256 threads, 64 queries (i) x 64 refs (j) tile, BK=16 over K=2304.
// K is ordered d-major (d = dy*3+dx in 0..8, 256 channels each) so the patch
// offset and rnorm loads hoist out of the channel-tile loop.
// ---------------------------------------------------------------------------
__global__ __launch_bounds__(256) void corr_kernel(const float* __restrict__ f1,
                                                   const float* __restrict__ f2,
                                                   const float* __restrict__ rnorm,
                                                   float* __restrict__ res_val,
                                                   int* __restrict__ res_idx) {
  int b = blockIdx.y;
  int itile = blockIdx.x;  // 0..60
  const float* fin = f1 + (size_t)b * C * HW;
  const float* fref = f2 + (size_t)b * C * HW;
  const float* rni = rnorm + (size_t)b * HW;
  const float* rnr = rnorm + (size_t)(BATCH + b) * HW;

  __shared__ float As[16][64];
  __shared__ float Bs[16][64];
  __shared__ float sv[16][64];
  __shared__ int si[16][64];

  int t = threadIdx.x;
  int nl = t & 63;   // staging column (query or ref index within tile)
  int kq = t >> 6;   // 0..3 (staging k-quad)
  int ti = t & 15;   // compute: i-quad
  int tj = t >> 4;   // compute: j-quad

  int ia = itile * 64 + nl;
  int iac = ia < NQ ? ia : NQ - 1;     // clamp (results discarded at write)
  int ay = iac / WW, ax = iac - ay * WW;

  float bestv[4];
  int besti[4];
#pragma unroll
  for (int a = 0; a < 4; ++a) { bestv[a] = -3.0e38f; besti[a] = 0; }

  for (int jt = 0; jt < ITILES; ++jt) {
    int jb = jt * 64 + nl;
    int jbc = jb < NQ ? jb : NQ - 1;   // clamp (skipped at compare)
    int byy = jbc / WW, bxx = jbc - byy * WW;

    float acc[4][4];
#pragma unroll
    for (int a = 0; a < 4; ++a)
#pragma unroll
      for (int c2 = 0; c2 < 4; ++c2) acc[a][c2] = 0.f;

    for (int d = 0; d < 9; ++d) {
      int dy = d / 3, dx = d - dy * 3;
      int apos = (ay + dy) * W + ax + dx;
      int bpos = (byy + dy) * W + bxx + dx;
      float arn = rni[apos];
      float brn = rnr[bpos];
      const float* aptr = fin + apos + (size_t)(kq * 4) * HW;
      const float* bptr = fref + bpos + (size_t)(kq * 4) * HW;
      for (int ct = 0; ct < 16; ++ct) {
        __syncthreads();  // previous compute done before overwrite
#pragma unroll
        for (int u = 0; u < 4; ++u) {
          As[kq * 4 + u][nl] = aptr[(size_t)(ct * 16 + u) * HW] * arn;
          Bs[kq * 4 + u][nl] = bptr[(size_t)(ct * 16 + u) * HW] * brn;
        }
        __syncthreads();
#pragma unroll
        for (int k = 0; k < 16; ++k) {
          const float4 a4 = *(const float4*)&As[k][ti * 4];
          const float4 b4 = *(const float4*)&Bs[k][tj * 4];
          float av[4] = {a4.x, a4.y, a4.z, a4.w};
          float bv[4] = {b4.x, b4.y, b4.z, b4.w};
#pragma unroll
          for (int a = 0; a < 4; ++a)
#pragma unroll
            for (int c2 = 0; c2 < 4; ++c2)
              acc[a][c2] = fmaf(av[a], bv[c2], acc[a][c2]);
        }
      }
    }

    // running argmax; strict > + ascending j preserves first-occurrence
#pragma unroll
    for (int c2 = 0; c2 < 4; ++c2) {
      int j = jt * 64 + tj * 4 + c2;
      bool ok = j < NQ;
#pragma unroll
      for (int a = 0; a < 4; ++a) {
        float v = acc[a][c2];
        if (ok && v > bestv[a]) { bestv[a] = v; besti[a] = j; }
      }
    }
  }

  // cross-thread (over tj) reduction per query; equal value -> smaller j
#pragma unroll
  for (int a = 0; a < 4; ++a) {
    sv[tj][ti * 4 + a] = bestv[a];
    si[tj][ti * 4 + a] = besti[a];
  }
  __syncthreads();
  if (t < 64) {
    float bv = sv[0][t];
    int bi = si[0][t];
#pragma unroll
    for (int r = 1; r < 16; ++r) {
      float v = sv[r][t];
      int ix = si[r][t];
      if (v > bv || (v == bv && ix < bi)) { bv = v; bi = ix; }
    }
    int ig = itile * 64 + t;
    if (ig < NQ) {
      res_val[(size_t)b * NQ + ig] = bv;
      res_idx[(size_t)b * NQ + ig] = bi;
    }
  }
}

// ---------------------------------------------------------------------------
// Kernel 3: assemble flow (B,64,64,2), offset (B,9,64,64,2), sim (B,1,64,64).
// Writes every output element (d_out is poisoned once before timing).
// ---------------------------------------------------------------------------
__global__ __launch_bounds__(256) void assemble_kernel(const float* __restrict__ res_val,
                                                       const int* __restrict__ res_idx,
                                                       float* __restrict__ out) {
  int gid = blockIdx.x * 256 + threadIdx.x;  // b*4096 + y*64 + x
  if (gid >= BATCH * HW) return;
  int b = gid >> 12;
  int y = (gid >> 6) & 63;
  int x = gid & 63;

  float* out_flow = out;                                     // (B,64,64,2)
  float* out_off = out + (size_t)BATCH * HW * 2;             // (B,9,64,64,2)
  float* out_sim = out + (size_t)BATCH * HW * 2 + (size_t)BATCH * 9 * HW * 2;

  auto flow_at = [&](int yy, int xx, float* fx, float* fy) {
    if (yy >= 0 && yy < HH && xx >= 0 && xx < WW) {
      int idx = res_idx[(size_t)b * NQ + yy * WW + xx];
      *fx = (float)(idx % WW - xx);
      *fy = (float)(idx / WW - yy);
    } else {
      *fx = 0.f;
      *fy = 0.f;
    }
  };

  float fx, fy;
  flow_at(y, x, &fx, &fy);
  size_t fo = ((size_t)b * HW + y * W + x) * 2;
  out_flow[fo + 0] = fx;
  out_flow[fo + 1] = fy;

#pragma unroll
  for (int s = 0; s < 9; ++s) {
    int i = s / 3, j = s % 3;
    float ox, oy;
    flow_at(y - i, x - j, &ox, &oy);
    size_t o = (((size_t)b * 9 + s) * HW + y * W + x) * 2;
    out_off[o + 0] = ox;
    out_off[o + 1] = oy;
  }

  float sim = 0.f;
  if (y >= 1 && y <= HH && x >= 1 && x <= WW) {
    float mv = res_val[(size_t)b * NQ + (y - 1) * WW + (x - 1)];
    sim = mv * (1.0f / ((3.0f + 1e-5f) * 3.0f));  // /(||Pr||+1e-5)/||Pi||, norms = 3
  }
  out_sim[(size_t)b * HW + y * W + x] = sim;
}

// ---------------------------------------------------------------------------
extern "C" void kernel_launch(void* const* d_in, const int* in_sizes, int n_in,
                              void* d_out, int out_size, void* d_ws, size_t ws_size,
                              hipStream_t stream) {
  const float* f1 = (const float*)d_in[0];
  const float* f2 = (const float*)d_in[1];
  float* out = (float*)d_out;

  // ws layout: rnorm [2*B*HW] f32 | res_val [B*NQ] f32 | res_idx [B*NQ] i32
  float* rnorm = (float*)d_ws;
  float* res_val = rnorm + 2 * BATCH * HW;
  int* res_idx = (int*)(res_val + BATCH * NQ);

  dim3 ngrid(BATCH * H, 2);
  norm_kernel<<<ngrid, 256, 0, stream>>>(f1, f2, rnorm);

  dim3 cgrid(ITILES, BATCH);
  corr_kernel<<<cgrid, 256, 0, stream>>>(f1, f2, rnorm, res_val, res_idx);

  int total = BATCH * HW;
  assemble_kernel<<<(total + 255) / 256, 256, 0, stream>>>(res_val, res_idx, out);
}

// Round 2
// 867.838 us; speedup vs baseline: 12.3425x; 12.3425x over previous
//
#include <hip/hip_runtime.h>

typedef unsigned short u16;
typedef unsigned int u32;
typedef __bf16 bf16x8 __attribute__((ext_vector_type(8)));
typedef float f32x4 __attribute__((ext_vector_type(4)));

constexpr int BATCH = 8;
constexpr int C = 256;
constexpr int H = 64;
constexpr int W = 64;
constexpr int HW = H * W;          // 4096
constexpr int HH = 62, WW = 62;    // valid patch grid
constexpr int NQ = HH * WW;        // 3844
constexpr size_t PSTRIDE = (size_t)4096 * 4096 + 64;  // + pad for edge overreads

// ws layout (bytes)
constexpr size_t OFF_RNORM = 0;                       // 2*8*4096*4 = 262144
constexpr size_t OFF_HI1 = 262144;                    // 8*4096*256*2 = 16777216
constexpr size_t OFF_LO1 = OFF_HI1 + 16777216;
constexpr size_t OFF_HI2 = OFF_LO1 + 16777216;
constexpr size_t OFF_LO2 = OFF_HI2 + 16777216;
constexpr size_t OFF_PVAL = OFF_LO2 + 16777216;       // 8*4*3844*4 = 492032
constexpr size_t OFF_PIDX = OFF_PVAL + 492032;
constexpr size_t OFF_RESV = OFF_PIDX + 492032;        // 8*3844*4 = 123008
constexpr size_t OFF_RESI = OFF_RESV + 123008;
constexpr size_t OFF_P = OFF_RESI + 123008;           // 67109120

// ---------------------------------------------------------------------------
// Kernel 1: per-position reciprocal channel-L2 norm. rnorm[tensor][b][pos]
// ---------------------------------------------------------------------------
__global__ __launch_bounds__(256) void norm_kernel(const float* __restrict__ f1,
                                                   const float* __restrict__ f2,
                                                   float* __restrict__ rnorm) {
  int by = blockIdx.x;           // b*H + y
  int tensor = blockIdx.y;
  const float* f = tensor ? f2 : f1;
  int b = by >> 6, y = by & 63;
  int x = threadIdx.x & 63;
  int cq = threadIdx.x >> 6;
  const float* base = f + ((size_t)b * C) * HW + y * W + x;
  float s = 0.f;
  for (int c = cq; c < C; c += 4) {
    float v = base[(size_t)c * HW];
    s = fmaf(v, v, s);
  }
  __shared__ float sm[4][64];
  sm[cq][x] = s;
  __syncthreads();
  if (threadIdx.x < 64) {
    float t = sm[0][x] + sm[1][x] + sm[2][x] + sm[3][x];
    float nrm = fmaxf(sqrtf(t), 1e-12f);
    rnorm[((size_t)tensor * BATCH + b) * HW + y * W + x] = 1.0f / nrm;
  }
}

// ---------------------------------------------------------------------------
// Kernel 2: normalize + hi/lo bf16 split + transpose to [b][pos][c] planes.
// ---------------------------------------------------------------------------
__global__ __launch_bounds__(256) void convert_kernel(const float* __restrict__ f1,
                                                      const float* __restrict__ f2,
                                                      const float* __restrict__ rnorm,
                                                      u16* __restrict__ hi1, u16* __restrict__ lo1,
                                                      u16* __restrict__ hi2, u16* __restrict__ lo2) {
  int chunk = blockIdx.x;        // 0..127, 32 positions each
  int bi = blockIdx.y;
  int tensor = blockIdx.z;
  int pos0 = chunk * 32;
  const float* f = (tensor ? f2 : f1) + (size_t)bi * C * HW;
  const float* rn = rnorm + ((size_t)tensor * BATCH + bi) * HW + pos0;
  u16* dh = (tensor ? hi2 : hi1) + ((size_t)bi * HW + pos0) * C;
  u16* dl = (tensor ? lo2 : lo1) + ((size_t)bi * HW + pos0) * C;

  __shared__ u32 sm[32][257];
  int t = threadIdx.x;
  int px = t & 31, cg = t >> 5;  // cg 0..7
  float r = rn[px];
  for (int k = 0; k < 32; ++k) {
    int c = cg * 32 + k;
    float v = f[(size_t)c * HW + pos0 + px] * r;
    __bf16 h = (__bf16)v;        // RNE
    float hf = (float)h;
    __bf16 lo = (__bf16)(v - hf);
    sm[px][c] = ((u32)__builtin_bit_cast(u16, h) << 16) | (u32)__builtin_bit_cast(u16, lo);
  }
  __syncthreads();
  int px2 = t >> 3, seg = t & 7;
  int c0 = seg * 32;
  for (int g8 = 0; g8 < 4; ++g8) {
    u32 hw0, hw1, hw2, hw3, lw0, lw1, lw2, lw3;
    u32 a, b2;
    a = sm[px2][c0 + g8 * 8 + 0]; b2 = sm[px2][c0 + g8 * 8 + 1];
    hw0 = (a >> 16) | (b2 & 0xFFFF0000u); lw0 = (a & 0xFFFFu) | (b2 << 16);
    a = sm[px2][c0 + g8 * 8 + 2]; b2 = sm[px2][c0 + g8 * 8 + 3];
    hw1 = (a >> 16) | (b2 & 0xFFFF0000u); lw1 = (a & 0xFFFFu) | (b2 << 16);
    a = sm[px2][c0 + g8 * 8 + 4]; b2 = sm[px2][c0 + g8 * 8 + 5];
    hw2 = (a >> 16) | (b2 & 0xFFFF0000u); lw2 = (a & 0xFFFFu) | (b2 << 16);
    a = sm[px2][c0 + g8 * 8 + 6]; b2 = sm[px2][c0 + g8 * 8 + 7];
    hw3 = (a >> 16) | (b2 & 0xFFFF0000u); lw3 = (a & 0xFFFFu) | (b2 << 16);
    size_t off = (size_t)px2 * C + c0 + g8 * 8;
    uint4 hv; hv.x = hw0; hv.y = hw1; hv.z = hw2; hv.w = hw3;
    uint4 lv; lv.x = lw0; lv.y = lw1; lv.z = lw2; lv.w = lw3;
    *(uint4*)(dh + off) = hv;
    *(uint4*)(dl + off) = lv;
  }
}

// ---------------------------------------------------------------------------
// Kernel 3: P = f1n^T * f2n per image (4096x4096x256), split-bf16 3-product
// MFMA. Tile 128x128, BK=64, 4 waves (64x64 quadrant each, 4x4 fragments).
// LDS layout per plane: [row 128][chunk 8 of 16B], chunk ^= (row&7) swizzle.
// ---------------------------------------------------------------------------
__global__ __launch_bounds__(256, 2) void pgemm_kernel(const u16* __restrict__ hi1,
                                                       const u16* __restrict__ lo1,
                                                       const u16* __restrict__ hi2,
                                                       const u16* __restrict__ lo2,
                                                       int bi, float* __restrict__ P) {
  int p0 = blockIdx.x * 128, q0 = blockIdx.y * 128;
  const u16* Ah = hi1 + ((size_t)bi * HW + p0) * C;
  const u16* Al = lo1 + ((size_t)bi * HW + p0) * C;
  const u16* Bh = hi2 + ((size_t)bi * HW + q0) * C;
  const u16* Bl = lo2 + ((size_t)bi * HW + q0) * C;

  __shared__ __align__(16) char smem[65536];
  char* sAh = smem;
  char* sAl = smem + 16384;
  char* sBh = smem + 32768;
  char* sBl = smem + 49152;

  int t = threadIdx.x;
  int l = t & 63, w = t >> 6, wm = w >> 1, wn = w & 1;
  int lr = l & 15, lh = l >> 4;

  f32x4 acc[4][4];
#pragma unroll
  for (int mf = 0; mf < 4; ++mf)
#pragma unroll
    for (int nf = 0; nf < 4; ++nf)
      acc[mf][nf] = (f32x4){0.f, 0.f, 0.f, 0.f};

  // staging role
  int sr = t & 127;
  bool isB = t >= 128;
  const u16* gh = (isB ? Bh : Ah) + (size_t)sr * C;
  const u16* gl = (isB ? Bl : Al) + (size_t)sr * C;
  char* dh = (isB ? sBh : sAh) + sr * 128;
  char* dl = (isB ? sBl : sAl) + sr * 128;
  int sw = (sr & 7) << 4;

  for (int kt = 0; kt < 4; ++kt) {
    if (kt) __syncthreads();
    const u16* ghk = gh + kt * 64;
    const u16* glk = gl + kt * 64;
#pragma unroll
    for (int cc = 0; cc < 8; ++cc) {
      uint4 v = *(const uint4*)(ghk + cc * 8);
      *(uint4*)(dh + (((cc << 4) ^ sw))) = v;
      uint4 v2 = *(const uint4*)(glk + cc * 8);
      *(uint4*)(dl + (((cc << 4) ^ sw))) = v2;
    }
    __syncthreads();
#pragma unroll
    for (int ks = 0; ks < 2; ++ks) {
      bf16x8 ah[4], al[4];
#pragma unroll
      for (int mf = 0; mf < 4; ++mf) {
        int row = wm * 64 + mf * 16 + lr;
        int off = row * 128 + ((((ks * 4 + lh) << 4)) ^ ((row & 7) << 4));
        ah[mf] = *(const bf16x8*)(sAh + off);
        al[mf] = *(const bf16x8*)(sAl + off);
      }
#pragma unroll
      for (int nf = 0; nf < 4; ++nf) {
        int row = wn * 64 + nf * 16 + lr;
        int off = row * 128 + ((((ks * 4 + lh) << 4)) ^ ((row & 7) << 4));
        bf16x8 bh = *(const bf16x8*)(sBh + off);
        bf16x8 bl = *(const bf16x8*)(sBl + off);
#pragma unroll
        for (int mf = 0; mf < 4; ++mf) {
          acc[mf][nf] = __builtin_amdgcn_mfma_f32_16x16x32_bf16(ah[mf], bh, acc[mf][nf], 0, 0, 0);
          acc[mf][nf] = __builtin_amdgcn_mfma_f32_16x16x32_bf16(al[mf], bh, acc[mf][nf], 0, 0, 0);
          acc[mf][nf] = __builtin_amdgcn_mfma_f32_16x16x32_bf16(ah[mf], bl, acc[mf][nf], 0, 0, 0);
        }
      }
    }
  }

  // C/D layout (m89-verified): col = lane&15, row = (lane>>4)*4 + reg
#pragma unroll
  for (int mf = 0; mf < 4; ++mf)
#pragma unroll
    for (int nf = 0; nf < 4; ++nf)
#pragma unroll
      for (int j = 0; j < 4; ++j) {
        int prow = p0 + wm * 64 + mf * 16 + lh * 4 + j;
        int qcol = q0 + wn * 64 + nf * 16 + lr;
        P[(size_t)prow * 4096 + qcol] = acc[mf][nf][j];
      }
}

// ---------------------------------------------------------------------------
// Kernel 4: diagonal 3x3 box-sum over P + running argmax.
// Block = (query row y, jy-split s). Thread: ix = t>>2, jx-group g = t&3.
// ---------------------------------------------------------------------------
__global__ __launch_bounds__(256) void reduce_kernel(const float* __restrict__ P, int bi,
                                                     float* __restrict__ pval,
                                                     int* __restrict__ pidx) {
  int y = blockIdx.x;            // 0..61
  int s = blockIdx.y;            // 0..3
  int t = threadIdx.x;
  int ix = t >> 2, g = t & 3;
  bool valid = ix < WW;
  float bestv = -3.0e38f;
  int bestj = 0;
  int jy0 = s * 16;
  int jy1 = jy0 + 16 > HH ? HH : jy0 + 16;

  if (valid) {
    for (int jy = jy0; jy < jy1; ++jy) {
      float c16[16];
#pragma unroll
      for (int k = 0; k < 16; ++k) c16[k] = 0.f;
#pragma unroll
      for (int dy = 0; dy < 3; ++dy) {
#pragma unroll
        for (int dx = 0; dx < 3; ++dx) {
          const float* row = P + (size_t)((y + dy) * 64 + ix + dx) * 4096 + (jy + dy) * 64 + g * 16;
          float4 v0 = *(const float4*)(row);
          float4 v1 = *(const float4*)(row + 4);
          float4 v2 = *(const float4*)(row + 8);
          float4 v3 = *(const float4*)(row + 12);
          float4 v4 = *(const float4*)(row + 16);
          float sarr[20];
          sarr[0] = v0.x; sarr[1] = v0.y; sarr[2] = v0.z; sarr[3] = v0.w;
          sarr[4] = v1.x; sarr[5] = v1.y; sarr[6] = v1.z; sarr[7] = v1.w;
          sarr[8] = v2.x; sarr[9] = v2.y; sarr[10] = v2.z; sarr[11] = v2.w;
          sarr[12] = v3.x; sarr[13] = v3.y; sarr[14] = v3.z; sarr[15] = v3.w;
          sarr[16] = v4.x; sarr[17] = v4.y; sarr[18] = v4.z; sarr[19] = v4.w;
#pragma unroll
          for (int k = 0; k < 16; ++k) c16[k] += sarr[k + dx];
        }
      }
      int jbase = jy * WW;
#pragma unroll
      for (int k = 0; k < 16; ++k) {
        int jx = g * 16 + k;
        if (jx < WW && c16[k] > bestv) { bestv = c16[k]; bestj = jbase + jx; }
      }
    }
  }
  // reduce across the 4 g-threads (lanes t^1, t^2); ties -> smaller j
#pragma unroll
  for (int m = 1; m < 4; m <<= 1) {
    float ov = __shfl_xor(bestv, m, 64);
    int oj = __shfl_xor(bestj, m, 64);
    if (ov > bestv || (ov == bestv && oj < bestj)) { bestv = ov; bestj = oj; }
  }
  if (valid && g == 0) {
    size_t o = ((size_t)bi * 4 + s) * NQ + y * WW + ix;
    pval[o] = bestv;
    pidx[o] = bestj;
  }
}

// ---------------------------------------------------------------------------
// Kernel 5: combine jy-split partials (ascending s preserves first-occurrence)
// ---------------------------------------------------------------------------
__global__ __launch_bounds__(256) void combine_kernel(const float* __restrict__ pval,
                                                      const int* __restrict__ pidx,
                                                      float* __restrict__ resv,
                                                      int* __restrict__ residx) {
  int gid = blockIdx.x * 256 + threadIdx.x;
  if (gid >= BATCH * NQ) return;
  int b = gid / NQ, i = gid - b * NQ;
  float bv = -3.0e38f;
  int bj = 0;
#pragma unroll
  for (int s = 0; s < 4; ++s) {
    size_t o = ((size_t)b * 4 + s) * NQ + i;
    float v = pval[o];
    int j = pidx[o];
    if (v > bv || (v == bv && j < bj)) { bv = v; bj = j; }
  }
  resv[(size_t)b * NQ + i] = bv;
  residx[(size_t)b * NQ + i] = bj;
}

// ---------------------------------------------------------------------------
// Kernel 6: assemble flow (B,64,64,2), offset (B,9,64,64,2), sim (B,1,64,64).
// ---------------------------------------------------------------------------
__global__ __launch_bounds__(256) void assemble_kernel(const float* __restrict__ res_val,
                                                       const int* __restrict__ res_idx,
                                                       float* __restrict__ out) {
  int gid = blockIdx.x * 256 + threadIdx.x;
  if (gid >= BATCH * HW) return;
  int b = gid >> 12;
  int y = (gid >> 6) & 63;
  int x = gid & 63;

  float* out_flow = out;
  float* out_off = out + (size_t)BATCH * HW * 2;
  float* out_sim = out + (size_t)BATCH * HW * 2 + (size_t)BATCH * 9 * HW * 2;

  auto flow_at = [&](int yy, int xx, float* fx, float* fy) {
    if (yy >= 0 && yy < HH && xx >= 0 && xx < WW) {
      int idx = res_idx[(size_t)b * NQ + yy * WW + xx];
      *fx = (float)(idx % WW - xx);
      *fy = (float)(idx / WW - yy);
    } else {
      *fx = 0.f;
      *fy = 0.f;
    }
  };

  float fx, fy;
  flow_at(y, x, &fx, &fy);
  size_t fo = ((size_t)b * HW + y * W + x) * 2;
  out_flow[fo + 0] = fx;
  out_flow[fo + 1] = fy;

#pragma unroll
  for (int sft = 0; sft < 9; ++sft) {
    int i = sft / 3, j = sft % 3;
    float ox, oy;
    flow_at(y - i, x - j, &ox, &oy);
    size_t o = (((size_t)b * 9 + sft) * HW + y * W + x) * 2;
    out_off[o + 0] = ox;
    out_off[o + 1] = oy;
  }

  float sim = 0.f;
  if (y >= 1 && y <= HH && x >= 1 && x <= WW) {
    float mv = res_val[(size_t)b * NQ + (y - 1) * WW + (x - 1)];
    sim = mv * (1.0f / ((3.0f + 1e-5f) * 3.0f));  // patch norms are exactly 3
  }
  out_sim[(size_t)b * HW + y * W + x] = sim;
}

// ---------------------------------------------------------------------------
extern "C" void kernel_launch(void* const* d_in, const int* in_sizes, int n_in,
                              void* d_out, int out_size, void* d_ws, size_t ws_size,
                              hipStream_t stream) {
  const float* f1 = (const float*)d_in[0];
  const float* f2 = (const float*)d_in[1];
  float* out = (float*)d_out;
  char* ws = (char*)d_ws;

  float* rnorm = (float*)(ws + OFF_RNORM);
  u16* hi1 = (u16*)(ws + OFF_HI1);
  u16* lo1 = (u16*)(ws + OFF_LO1);
  u16* hi2 = (u16*)(ws + OFF_HI2);
  u16* lo2 = (u16*)(ws + OFF_LO2);
  float* pval = (float*)(ws + OFF_PVAL);
  int* pidx = (int*)(ws + OFF_PIDX);
  float* resv = (float*)(ws + OFF_RESV);
  int* residx = (int*)(ws + OFF_RESI);
  float* P = (float*)(ws + OFF_P);

  norm_kernel<<<dim3(BATCH * H, 2), 256, 0, stream>>>(f1, f2, rnorm);
  convert_kernel<<<dim3(128, BATCH, 2), 256, 0, stream>>>(f1, f2, rnorm, hi1, lo1, hi2, lo2);

  for (int b = 0; b < BATCH; ++b) {
    pgemm_kernel<<<dim3(32, 32), 256, 0, stream>>>(hi1, lo1, hi2, lo2, b, P);
    reduce_kernel<<<dim3(62, 4), 256, 0, stream>>>(P, b, pval, pidx);
  }

  combine_kernel<<<(BATCH * NQ + 255) / 256, 256, 0, stream>>>(pval, pidx, resv, residx);

  int total = BATCH * HW;
  assemble_kernel<<<(total + 255) / 256, 256, 0, stream>>>(resv, residx, out);
}

// Round 3
// 721.734 us; speedup vs baseline: 14.8410x; 1.2024x over previous
//
#include <hip/hip_runtime.h>

typedef unsigned short u16;
typedef unsigned int u32;
typedef __bf16 bf16x8 __attribute__((ext_vector_type(8)));
typedef float f32x4 __attribute__((ext_vector_type(4)));

constexpr int BATCH = 8;
constexpr int C = 256;
constexpr int H = 64;
constexpr int W = 64;
constexpr int HW = H * W;          // 4096
constexpr int HH = 62, WW = 62;    // valid patch grid
constexpr int NQ = HH * WW;        // 3844
constexpr int NBLK_RED = 300;      // sum over diagonals of ceil(L/16)

// ws layout (bytes)
constexpr size_t OFF_RNORM = 0;            // 2*8*4096*4 = 262144
constexpr size_t OFF_RESV = 262144;        // 8*3844*4 = 123008 (pad 123136)
constexpr size_t OFF_RESI = 385280;
constexpr size_t OFF_SLOT0 = 508416;
// per-slot layout
constexpr size_t SP_OP1 = 0;               // 4096*256*4 = 4,194,304 (packed u32 hi|lo)
constexpr size_t SP_OP2 = 4194304;
constexpr size_t SP_P = 8388608;           // 4096 planes * 16KB = 67,108,864
constexpr size_t SP_PVAL = 75497472;       // 123*62*62*4 = 1,891,248
constexpr size_t SP_PIDX = 77388720;
constexpr size_t SLOT_BYTES = 79280128;    // padded

// ---------------------------------------------------------------------------
// Kernel 1: per-position reciprocal channel-L2 norm. rnorm[tensor][b][pos]
// ---------------------------------------------------------------------------
__global__ __launch_bounds__(256) void norm_kernel(const float* __restrict__ f1,
                                                   const float* __restrict__ f2,
                                                   float* __restrict__ rnorm) {
  int by = blockIdx.x;           // b*H + y
  int tensor = blockIdx.y;
  const float* f = tensor ? f2 : f1;
  int b = by >> 6, y = by & 63;
  int x = threadIdx.x & 63;
  int cq = threadIdx.x >> 6;
  const float* base = f + ((size_t)b * C) * HW + y * W + x;
  float s = 0.f;
  for (int c = cq; c < C; c += 4) {
    float v = base[(size_t)c * HW];
    s = fmaf(v, v, s);
  }
  __shared__ float sm[4][64];
  sm[cq][x] = s;
  __syncthreads();
  if (threadIdx.x < 64) {
    float t = sm[0][x] + sm[1][x] + sm[2][x] + sm[3][x];
    float nrm = fmaxf(sqrtf(t), 1e-12f);
    rnorm[((size_t)tensor * BATCH + b) * HW + y * W + x] = 1.0f / nrm;
  }
}

// ---------------------------------------------------------------------------
// Kernel 2: normalize + hi/lo bf16 split, packed (hi<<16)|lo, [pos][c] layout.
// Per-image (slot) dispatch.
// ---------------------------------------------------------------------------
__global__ __launch_bounds__(256) void convert_kernel(const float* __restrict__ f1,
                                                      const float* __restrict__ f2,
                                                      const float* __restrict__ rnorm,
                                                      int bi,
                                                      u32* __restrict__ phl1,
                                                      u32* __restrict__ phl2) {
  int chunk = blockIdx.x;        // 0..127, 32 positions each
  int tensor = blockIdx.y;
  int pos0 = chunk * 32;
  const float* f = (tensor ? f2 : f1) + (size_t)bi * C * HW;
  const float* rn = rnorm + ((size_t)tensor * BATCH + bi) * HW + pos0;
  u32* dst = tensor ? phl2 : phl1;

  __shared__ u32 sm[32][257];
  int t = threadIdx.x;
  int px = t & 31, cg = t >> 5;  // cg 0..7
  float r = rn[px];
  for (int kk = 0; kk < 32; ++kk) {
    int c = (cg << 5) + kk;
    float v = f[(size_t)c * HW + pos0 + px] * r;
    __bf16 h = (__bf16)v;        // RNE
    float hf = (float)h;
    __bf16 lo = (__bf16)(v - hf);
    sm[px][c] = ((u32)__builtin_bit_cast(u16, h) << 16) | (u32)__builtin_bit_cast(u16, lo);
  }
  __syncthreads();
  for (int it = 0; it < 32; ++it) {
    int gid = it * 256 + t;
    int px2 = gid >> 8, c = gid & 255;
    dst[(size_t)(pos0 + px2) * 256 + c] = sm[px2][c];
  }
}

// ---------------------------------------------------------------------------
// Kernel 3: P = f1n^T * f2n (4096x4096x256), split-bf16 3-product MFMA.
// Packed-u32 operands unpacked during staging. Output in PLANE-MAJOR layout:
// P[((r*64+c))*4096 + x*64 + bx] where p = r*64+x (query), q = c*64+bx (ref).
// ---------------------------------------------------------------------------
__global__ __launch_bounds__(256, 2) void pgemm_kernel(const u32* __restrict__ pka,
                                                       const u32* __restrict__ pkb,
                                                       float* __restrict__ P) {
  int bid = blockIdx.x;
  int swz = (bid & 7) * 128 + (bid >> 3);   // bijective XCD swizzle (1024 blocks)
  int p0 = (swz >> 5) << 7, q0 = (swz & 31) << 7;

  __shared__ __align__(16) char smem[65536];
  char* sAh = smem;
  char* sAl = smem + 16384;
  char* sBh = smem + 32768;
  char* sBl = smem + 49152;

  int t = threadIdx.x;
  int l = t & 63, w = t >> 6, wm = w >> 1, wn = w & 1;
  int lr = l & 15, lh = l >> 4;

  f32x4 acc[4][4];
#pragma unroll
  for (int mf = 0; mf < 4; ++mf)
#pragma unroll
    for (int nf = 0; nf < 4; ++nf)
      acc[mf][nf] = (f32x4){0.f, 0.f, 0.f, 0.f};

  // staging role: 128 threads A, 128 threads B; one row (position) each
  int sr = t & 127;
  bool isB = t >= 128;
  const u32* gsrc = (isB ? pkb : pka) + ((size_t)(isB ? q0 : p0) + sr) * 256;
  char* dh = (isB ? sBh : sAh) + sr * 128;
  char* dl = (isB ? sBl : sAl) + sr * 128;
  int sw = (sr & 7) << 4;

  for (int kt = 0; kt < 4; ++kt) {
    if (kt) __syncthreads();
    const uint4* gp = (const uint4*)(gsrc + kt * 64);
#pragma unroll
    for (int cc = 0; cc < 8; ++cc) {
      uint4 pa = gp[2 * cc], pb = gp[2 * cc + 1];
      uint4 hv, lv;
      hv.x = (pa.x >> 16) | (pa.y & 0xFFFF0000u);  lv.x = (pa.x & 0xFFFFu) | (pa.y << 16);
      hv.y = (pa.z >> 16) | (pa.w & 0xFFFF0000u);  lv.y = (pa.z & 0xFFFFu) | (pa.w << 16);
      hv.z = (pb.x >> 16) | (pb.y & 0xFFFF0000u);  lv.z = (pb.x & 0xFFFFu) | (pb.y << 16);
      hv.w = (pb.z >> 16) | (pb.w & 0xFFFF0000u);  lv.w = (pb.z & 0xFFFFu) | (pb.w << 16);
      *(uint4*)(dh + ((cc << 4) ^ sw)) = hv;
      *(uint4*)(dl + ((cc << 4) ^ sw)) = lv;
    }
    __syncthreads();
#pragma unroll
    for (int ks = 0; ks < 2; ++ks) {
      bf16x8 ah[4], al[4];
#pragma unroll
      for (int mf = 0; mf < 4; ++mf) {
        int row = wm * 64 + mf * 16 + lr;
        int off = row * 128 + ((((ks * 4 + lh) << 4)) ^ ((row & 7) << 4));
        ah[mf] = *(const bf16x8*)(sAh + off);
        al[mf] = *(const bf16x8*)(sAl + off);
      }
#pragma unroll
      for (int nf = 0; nf < 4; ++nf) {
        int row = wn * 64 + nf * 16 + lr;
        int off = row * 128 + ((((ks * 4 + lh) << 4)) ^ ((row & 7) << 4));
        bf16x8 bh = *(const bf16x8*)(sBh + off);
        bf16x8 bl = *(const bf16x8*)(sBl + off);
#pragma unroll
        for (int mf = 0; mf < 4; ++mf) {
          acc[mf][nf] = __builtin_amdgcn_mfma_f32_16x16x32_bf16(ah[mf], bh, acc[mf][nf], 0, 0, 0);
          acc[mf][nf] = __builtin_amdgcn_mfma_f32_16x16x32_bf16(al[mf], bh, acc[mf][nf], 0, 0, 0);
          acc[mf][nf] = __builtin_amdgcn_mfma_f32_16x16x32_bf16(ah[mf], bl, acc[mf][nf], 0, 0, 0);
        }
      }
    }
  }

  // C/D layout (m89-verified): col = lane&15, row = (lane>>4)*4 + reg
#pragma unroll
  for (int mf = 0; mf < 4; ++mf)
#pragma unroll
    for (int nf = 0; nf < 4; ++nf)
#pragma unroll
      for (int j = 0; j < 4; ++j) {
        int pg = p0 + wm * 64 + mf * 16 + lh * 4 + j;
        int qg = q0 + wn * 64 + nf * 16 + lr;
        size_t addr = (((size_t)((pg >> 6) << 6 | (qg >> 6))) << 12) +
                      ((pg & 63) << 6) + (qg & 63);
        P[addr] = acc[mf][nf][j];
      }
}

// ---------------------------------------------------------------------------
// Kernel 4: diagonal-rolling reduce. Block = (diagonal k segment, slot).
// LDS ring of 4 transposed planes T[bx][ax] (stride 66). 9 adds per corr
// from LDS; per-step per-wave bx-group scan; per (y,jy,ax) candidate written
// to partial[ki][y][ax]. Register prefetch hides plane-load latency.
// ---------------------------------------------------------------------------
constexpr int PW = 64 * 66;

__global__ __launch_bounds__(512) void reduce_kernel(const float* __restrict__ Pb,
                                                     float* __restrict__ pvb,
                                                     int* __restrict__ pib,
                                                     size_t slotElems) {
  int slot = blockIdx.y;
  const float* P = Pb + (size_t)slot * slotElems;
  float* pval = pvb + (size_t)slot * slotElems;
  int* pidx = pib + (size_t)slot * slotElems;

  // map blockIdx.x -> (ki, seg)
  int bid = blockIdx.x;
  int ki = 0;
  for (ki = 0; ki < 123; ++ki) {
    int d = ki - 61; if (d < 0) d = -d;
    int ns = (62 - d + 15) >> 4;
    if (bid < ns) break;
    bid -= ns;
  }
  int k = ki - 61;
  int ystart = k < 0 ? -k : 0;
  int yend = k > 0 ? 61 - k : 61;
  int y0 = ystart + bid * 16;
  int y1 = y0 + 16; if (y1 > yend + 1) y1 = yend + 1;

  __shared__ float T[4][PW];
  __shared__ float cv[8][64];
  __shared__ int ci[8][64];

  int t = threadIdx.x;
  int w = t >> 6, l = t & 63;

  // prologue: load planes r = y0..y0+2
  for (int r = y0; r < y0 + 3; ++r) {
    const float* gp = P + ((size_t)((r << 6) + (r + k)) << 12);
    float* Ts = T[r & 3];
#pragma unroll
    for (int it = 0; it < 2; ++it) {
      int gid = it * 512 + t;
      int x = gid >> 4, bx0 = (gid & 15) << 2;
      float4 v = *(const float4*)(gp + (x << 6) + bx0);
      Ts[(bx0 + 0) * 66 + x] = v.x;
      Ts[(bx0 + 1) * 66 + x] = v.y;
      Ts[(bx0 + 2) * 66 + x] = v.z;
      Ts[(bx0 + 3) * 66 + x] = v.w;
    }
  }
  __syncthreads();

  for (int y = y0; y < y1; ++y) {
    // issue prefetch of plane r = y+3 (needed next step)
    float4 pf0, pf1;
    bool dopf = (y + 1 < y1);
    if (dopf) {
      const float* gp = P + ((size_t)(((y + 3) << 6) + (y + 3 + k)) << 12);
      pf0 = *(const float4*)(gp + ((t >> 4) << 6) + ((t & 15) << 2));
      int g1 = 512 + t;
      pf1 = *(const float4*)(gp + ((g1 >> 4) << 6) + ((g1 & 15) << 2));
    }
    const float* T0 = T[y & 3];
    const float* T1 = T[(y + 1) & 3];
    const float* T2 = T[(y + 2) & 3];
    float best = -3.0e38f; int bbx = 0;
#pragma unroll
    for (int bb = 0; bb < 8; ++bb) {
      int bx = (w << 3) + bb;
      if (bx > 61) break;           // wave-uniform
      int r0 = bx * 66 + l;
      float s = T0[r0] + T0[r0 + 67] + T0[r0 + 134]
              + T1[r0] + T1[r0 + 67] + T1[r0 + 134]
              + T2[r0] + T2[r0 + 67] + T2[r0 + 134];
      if (s > best) { best = s; bbx = bx; }   // ascending bx: first max
    }
    cv[w][l] = best; ci[w][l] = bbx;
    __syncthreads();
    if (w == 0) {
      float bv = cv[0][l]; int bj = ci[0][l];
#pragma unroll
      for (int ww = 1; ww < 8; ++ww) {
        float v = cv[ww][l];
        if (v > bv) { bv = v; bj = ci[ww][l]; }  // ascending bx ranges
      }
      if (l <= 61) {
        int o = (ki * 62 + y) * 62 + l;
        pval[o] = bv; pidx[o] = bj;
      }
    }
    if (dopf) {
      float* Ts = T[(y + 3) & 3];   // overwrites retired plane y-1: safe
      int x0 = t >> 4, b0x = (t & 15) << 2;
      Ts[(b0x + 0) * 66 + x0] = pf0.x; Ts[(b0x + 1) * 66 + x0] = pf0.y;
      Ts[(b0x + 2) * 66 + x0] = pf0.z; Ts[(b0x + 3) * 66 + x0] = pf0.w;
      int g1 = 512 + t;
      int x1 = g1 >> 4, b1x = (g1 & 15) << 2;
      Ts[(b1x + 0) * 66 + x1] = pf1.x; Ts[(b1x + 1) * 66 + x1] = pf1.y;
      Ts[(b1x + 2) * 66 + x1] = pf1.z; Ts[(b1x + 3) * 66 + x1] = pf1.w;
    }
    __syncthreads();
  }
}

// ---------------------------------------------------------------------------
// Kernel 5: combine diagonal partials over jy (ascending -> first occurrence)
// ---------------------------------------------------------------------------
__global__ __launch_bounds__(256) void combine_kernel(const float* __restrict__ pv0,
                                                      const int* __restrict__ pi0,
                                                      size_t slotElems, int b0,
                                                      float* __restrict__ resv,
                                                      int* __restrict__ residx) {
  int q = blockIdx.x * 256 + threadIdx.x;
  if (q >= NQ) return;
  int slot = blockIdx.y;
  int b = b0 + slot;
  const float* pv = pv0 + (size_t)slot * slotElems;
  const int* pi = pi0 + (size_t)slot * slotElems;
  int y = q / 62, ax = q - y * 62;
  float bv = -3.0e38f; int bj = 0;
  for (int jy = 0; jy < 62; ++jy) {
    int ki = 61 + jy - y;
    int o = (ki * 62 + y) * 62 + ax;
    float v = pv[o];
    if (v > bv) { bv = v; bj = jy * 62 + pi[o]; }
  }
  resv[(size_t)b * NQ + q] = bv;
  residx[(size_t)b * NQ + q] = bj;
}

// ---------------------------------------------------------------------------
// Kernel 6: assemble flow (B,64,64,2), offset (B,9,64,64,2), sim (B,1,64,64).
// ---------------------------------------------------------------------------
__global__ __launch_bounds__(256) void assemble_kernel(const float* __restrict__ res_val,
                                                       const int* __restrict__ res_idx,
                                                       float* __restrict__ out) {
  int gid = blockIdx.x * 256 + threadIdx.x;
  if (gid >= BATCH * HW) return;
  int b = gid >> 12;
  int y = (gid >> 6) & 63;
  int x = gid & 63;

  float* out_flow = out;
  float* out_off = out + (size_t)BATCH * HW * 2;
  float* out_sim = out + (size_t)BATCH * HW * 2 + (size_t)BATCH * 9 * HW * 2;

  auto flow_at = [&](int yy, int xx, float* fx, float* fy) {
    if (yy >= 0 && yy < HH && xx >= 0 && xx < WW) {
      int idx = res_idx[(size_t)b * NQ + yy * WW + xx];
      *fx = (float)(idx % WW - xx);
      *fy = (float)(idx / WW - yy);
    } else {
      *fx = 0.f;
      *fy = 0.f;
    }
  };

  float fx, fy;
  flow_at(y, x, &fx, &fy);
  size_t fo = ((size_t)b * HW + y * W + x) * 2;
  out_flow[fo + 0] = fx;
  out_flow[fo + 1] = fy;

#pragma unroll
  for (int sft = 0; sft < 9; ++sft) {
    int i = sft / 3, j = sft % 3;
    float ox, oy;
    flow_at(y - i, x - j, &ox, &oy);
    size_t o = (((size_t)b * 9 + sft) * HW + y * W + x) * 2;
    out_off[o + 0] = ox;
    out_off[o + 1] = oy;
  }

  float sim = 0.f;
  if (y >= 1 && y <= HH && x >= 1 && x <= WW) {
    float mv = res_val[(size_t)b * NQ + (y - 1) * WW + (x - 1)];
    sim = mv * (1.0f / ((3.0f + 1e-5f) * 3.0f));  // patch norms are exactly 3
  }
  out_sim[(size_t)b * HW + y * W + x] = sim;
}

// ---------------------------------------------------------------------------
extern "C" void kernel_launch(void* const* d_in, const int* in_sizes, int n_in,
                              void* d_out, int out_size, void* d_ws, size_t ws_size,
                              hipStream_t stream) {
  const float* f1 = (const float*)d_in[0];
  const float* f2 = (const float*)d_in[1];
  float* out = (float*)d_out;
  char* ws = (char*)d_ws;

  float* rnorm = (float*)(ws + OFF_RNORM);
  float* resv = (float*)(ws + OFF_RESV);
  int* residx = (int*)(ws + OFF_RESI);
  char* slot0 = ws + OFF_SLOT0;

  // adaptive image-group size from available workspace (deterministic)
  int nslots = 1;
  if (ws_size > OFF_SLOT0 + SLOT_BYTES) {
    size_t n = (ws_size - OFF_SLOT0) / SLOT_BYTES;
    nslots = n >= 8 ? 8 : (int)n;
    if (nslots < 1) nslots = 1;
  }
  size_t slotElems = SLOT_BYTES / 4;

  norm_kernel<<<dim3(BATCH * H, 2), 256, 0, stream>>>(f1, f2, rnorm);

  for (int b0 = 0; b0 < BATCH; b0 += nslots) {
    int g = BATCH - b0 < nslots ? BATCH - b0 : nslots;
    for (int i = 0; i < g; ++i) {
      char* slot = slot0 + (size_t)i * SLOT_BYTES;
      convert_kernel<<<dim3(128, 2), 256, 0, stream>>>(
          f1, f2, rnorm, b0 + i, (u32*)(slot + SP_OP1), (u32*)(slot + SP_OP2));
      pgemm_kernel<<<1024, 256, 0, stream>>>(
          (const u32*)(slot + SP_OP1), (const u32*)(slot + SP_OP2),
          (float*)(slot + SP_P));
    }
    reduce_kernel<<<dim3(NBLK_RED, g), 512, 0, stream>>>(
        (const float*)(slot0 + SP_P), (float*)(slot0 + SP_PVAL),
        (int*)(slot0 + SP_PIDX), slotElems);
    combine_kernel<<<dim3(16, g), 256, 0, stream>>>(
        (const float*)(slot0 + SP_PVAL), (const int*)(slot0 + SP_PIDX),
        slotElems, b0, resv, residx);
  }

  int total = BATCH * HW;
  assemble_kernel<<<(total + 255) / 256, 256, 0, stream>>>(resv, residx, out);
}

// Round 4
// 666.886 us; speedup vs baseline: 16.0616x; 1.0822x over previous
//
#include <hip/hip_runtime.h>

typedef unsigned short u16;
typedef unsigned int u32;
typedef __bf16 bf16x8 __attribute__((ext_vector_type(8)));
typedef float f32x4 __attribute__((ext_vector_type(4)));

constexpr int BATCH = 8;
constexpr int C = 256;
constexpr int H = 64;
constexpr int W = 64;
constexpr int HW = H * W;          // 4096
constexpr int HH = 62, WW = 62;    // valid patch grid
constexpr int NQ = HH * WW;        // 3844
constexpr int SEG = 8;             // y-steps per reduce block
constexpr int NBLK_RED = 536;      // sum over diagonals of ceil(len/SEG)

// ws layout (bytes)
constexpr size_t OFF_RNORM = 0;            // 2*8*4096*4 = 262144
constexpr size_t OFF_RESV = 262144;        // 8*3844*4 = 123008 (pad 123136)
constexpr size_t OFF_RESI = 385280;
constexpr size_t OFF_SLOT0 = 508416;
// per-slot layout
constexpr size_t SP_OP1 = 0;               // 4096*256*4 = 4,194,304 (packed u32 hi|lo)
constexpr size_t SP_OP2 = 4194304;
constexpr size_t SP_P = 8388608;           // 4096 planes * 16KB = 67,108,864
constexpr size_t SP_PVAL = 75497472;       // 123*62*62*4 = 1,891,248
constexpr size_t SP_PIDX = 77388720;
constexpr size_t SLOT_BYTES = 79280128;    // padded

// ---------------------------------------------------------------------------
// Kernel 1: per-position reciprocal channel-L2 norm. rnorm[tensor][b][pos]
// ---------------------------------------------------------------------------
__global__ __launch_bounds__(256) void norm_kernel(const float* __restrict__ f1,
                                                   const float* __restrict__ f2,
                                                   float* __restrict__ rnorm) {
  int by = blockIdx.x;           // b*H + y
  int tensor = blockIdx.y;
  const float* f = tensor ? f2 : f1;
  int b = by >> 6, y = by & 63;
  int x = threadIdx.x & 63;
  int cq = threadIdx.x >> 6;
  const float* base = f + ((size_t)b * C) * HW + y * W + x;
  float s = 0.f;
  for (int c = cq; c < C; c += 4) {
    float v = base[(size_t)c * HW];
    s = fmaf(v, v, s);
  }
  __shared__ float sm[4][64];
  sm[cq][x] = s;
  __syncthreads();
  if (threadIdx.x < 64) {
    float t = sm[0][x] + sm[1][x] + sm[2][x] + sm[3][x];
    float nrm = fmaxf(sqrtf(t), 1e-12f);
    rnorm[((size_t)tensor * BATCH + b) * HW + y * W + x] = 1.0f / nrm;
  }
}

// ---------------------------------------------------------------------------
// Kernel 2: normalize + hi/lo bf16 split, packed (hi<<16)|lo, [pos][c] layout.
// ---------------------------------------------------------------------------
__global__ __launch_bounds__(256) void convert_kernel(const float* __restrict__ f1,
                                                      const float* __restrict__ f2,
                                                      const float* __restrict__ rnorm,
                                                      int bi,
                                                      u32* __restrict__ phl1,
                                                      u32* __restrict__ phl2) {
  int chunk = blockIdx.x;        // 0..127, 32 positions each
  int tensor = blockIdx.y;
  int pos0 = chunk * 32;
  const float* f = (tensor ? f2 : f1) + (size_t)bi * C * HW;
  const float* rn = rnorm + ((size_t)tensor * BATCH + bi) * HW + pos0;
  u32* dst = tensor ? phl2 : phl1;

  __shared__ u32 sm[32][257];
  int t = threadIdx.x;
  int px = t & 31, cg = t >> 5;  // cg 0..7
  float r = rn[px];
  for (int kk = 0; kk < 32; ++kk) {
    int c = (cg << 5) + kk;
    float v = f[(size_t)c * HW + pos0 + px] * r;
    __bf16 h = (__bf16)v;        // RNE
    float hf = (float)h;
    __bf16 lo = (__bf16)(v - hf);
    sm[px][c] = ((u32)__builtin_bit_cast(u16, h) << 16) | (u32)__builtin_bit_cast(u16, lo);
  }
  __syncthreads();
  for (int it = 0; it < 32; ++it) {
    int gid = it * 256 + t;
    int px2 = gid >> 8, c = gid & 255;
    dst[(size_t)(pos0 + px2) * 256 + c] = sm[px2][c];
  }
}

// ---------------------------------------------------------------------------
// Kernel 3: P = f1n^T * f2n (4096x4096x256), split-bf16 3-product MFMA.
// Output in PLANE-MAJOR layout: plane (prow>>6, qcol>>6), offset
// (prow&63)*64 + (qcol&63). (Unchanged this round — profiling target.)
// ---------------------------------------------------------------------------
__global__ __launch_bounds__(256, 2) void pgemm_kernel(const u32* __restrict__ pka,
                                                       const u32* __restrict__ pkb,
                                                       float* __restrict__ P) {
  int bid = blockIdx.x;
  int swz = (bid & 7) * 128 + (bid >> 3);   // bijective XCD swizzle (1024 blocks)
  int p0 = (swz >> 5) << 7, q0 = (swz & 31) << 7;

  __shared__ __align__(16) char smem[65536];
  char* sAh = smem;
  char* sAl = smem + 16384;
  char* sBh = smem + 32768;
  char* sBl = smem + 49152;

  int t = threadIdx.x;
  int l = t & 63, w = t >> 6, wm = w >> 1, wn = w & 1;
  int lr = l & 15, lh = l >> 4;

  f32x4 acc[4][4];
#pragma unroll
  for (int mf = 0; mf < 4; ++mf)
#pragma unroll
    for (int nf = 0; nf < 4; ++nf)
      acc[mf][nf] = (f32x4){0.f, 0.f, 0.f, 0.f};

  // staging role: 128 threads A, 128 threads B; one row (position) each
  int sr = t & 127;
  bool isB = t >= 128;
  const u32* gsrc = (isB ? pkb : pka) + ((size_t)(isB ? q0 : p0) + sr) * 256;
  char* dh = (isB ? sBh : sAh) + sr * 128;
  char* dl = (isB ? sBl : sAl) + sr * 128;
  int sw = (sr & 7) << 4;

  for (int kt = 0; kt < 4; ++kt) {
    if (kt) __syncthreads();
    const uint4* gp = (const uint4*)(gsrc + kt * 64);
#pragma unroll
    for (int cc = 0; cc < 8; ++cc) {
      uint4 pa = gp[2 * cc], pb = gp[2 * cc + 1];
      uint4 hv, lv;
      hv.x = (pa.x >> 16) | (pa.y & 0xFFFF0000u);  lv.x = (pa.x & 0xFFFFu) | (pa.y << 16);
      hv.y = (pa.z >> 16) | (pa.w & 0xFFFF0000u);  lv.y = (pa.z & 0xFFFFu) | (pa.w << 16);
      hv.z = (pb.x >> 16) | (pb.y & 0xFFFF0000u);  lv.z = (pb.x & 0xFFFFu) | (pb.y << 16);
      hv.w = (pb.z >> 16) | (pb.w & 0xFFFF0000u);  lv.w = (pb.z & 0xFFFFu) | (pb.w << 16);
      *(uint4*)(dh + ((cc << 4) ^ sw)) = hv;
      *(uint4*)(dl + ((cc << 4) ^ sw)) = lv;
    }
    __syncthreads();
#pragma unroll
    for (int ks = 0; ks < 2; ++ks) {
      bf16x8 ah[4], al[4];
#pragma unroll
      for (int mf = 0; mf < 4; ++mf) {
        int row = wm * 64 + mf * 16 + lr;
        int off = row * 128 + ((((ks * 4 + lh) << 4)) ^ ((row & 7) << 4));
        ah[mf] = *(const bf16x8*)(sAh + off);
        al[mf] = *(const bf16x8*)(sAl + off);
      }
#pragma unroll
      for (int nf = 0; nf < 4; ++nf) {
        int row = wn * 64 + nf * 16 + lr;
        int off = row * 128 + ((((ks * 4 + lh) << 4)) ^ ((row & 7) << 4));
        bf16x8 bh = *(const bf16x8*)(sBh + off);
        bf16x8 bl = *(const bf16x8*)(sBl + off);
#pragma unroll
        for (int mf = 0; mf < 4; ++mf) {
          acc[mf][nf] = __builtin_amdgcn_mfma_f32_16x16x32_bf16(ah[mf], bh, acc[mf][nf], 0, 0, 0);
          acc[mf][nf] = __builtin_amdgcn_mfma_f32_16x16x32_bf16(al[mf], bh, acc[mf][nf], 0, 0, 0);
          acc[mf][nf] = __builtin_amdgcn_mfma_f32_16x16x32_bf16(ah[mf], bl, acc[mf][nf], 0, 0, 0);
        }
      }
    }
  }

  // C/D layout (m89-verified): col = lane&15, row = (lane>>4)*4 + reg
#pragma unroll
  for (int mf = 0; mf < 4; ++mf)
#pragma unroll
    for (int nf = 0; nf < 4; ++nf)
#pragma unroll
      for (int j = 0; j < 4; ++j) {
        int pg = p0 + wm * 64 + mf * 16 + lh * 4 + j;
        int qg = q0 + wn * 64 + nf * 16 + lr;
        size_t addr = (((size_t)((pg >> 6) << 6 | (qg >> 6))) << 12) +
                      ((pg & 63) << 6) + (qg & 63);
        P[addr] = acc[mf][nf][j];
      }
}

// ---------------------------------------------------------------------------
// Kernel 4: diagonal-rolling reduce, ring-3 + stride-65 (conflict-free).
// Block = (diagonal k, 8-step segment) x slot. LDS ring of 3 transposed
// planes T[bx][ax] stride 65. Per step: 9 LDS adds per (ax,bx) candidate,
// per-wave bx-range scan (lane=ax), cross-wave argmax via cv/ci, register
// prefetch of plane y+3 written into the retired slot y%3 after compute.
// ---------------------------------------------------------------------------
constexpr int PW = 64 * 65 + 64;   // 4224 words (pad covers diagonal tail reads)

__global__ __launch_bounds__(512, 6) void reduce_kernel(const float* __restrict__ Pb,
                                                        float* __restrict__ pvb,
                                                        int* __restrict__ pib,
                                                        size_t slotElems) {
  int slot = blockIdx.y;
  const float* P = Pb + (size_t)slot * slotElems;
  float* pval = pvb + (size_t)slot * slotElems;
  int* pidx = pib + (size_t)slot * slotElems;

  // map blockIdx.x -> (ki, seg)
  int bid = blockIdx.x;
  int ki = 0;
  for (ki = 0; ki < 123; ++ki) {
    int d = ki - 61; if (d < 0) d = -d;
    int ns = (62 - d + SEG - 1) / SEG;
    if (bid < ns) break;
    bid -= ns;
  }
  int k = ki - 61;
  int ystart = k < 0 ? -k : 0;
  int yend = k > 0 ? 61 - k : 61;
  int y0 = ystart + bid * SEG;
  int y1 = y0 + SEG; if (y1 > yend + 1) y1 = yend + 1;

  __shared__ float T[3][PW];
  __shared__ float cv[8][64];
  __shared__ unsigned char ci[8][64];

  int t = threadIdx.x;
  int w = t >> 6, l = t & 63;

  // prologue: load planes r = y0..y0+2 (always valid: r<=63, 0<=r+k<=63)
  for (int r = y0; r < y0 + 3; ++r) {
    const float* gp = P + ((size_t)((r << 6) + (r + k)) << 12);
    float* Ts = T[r % 3];
#pragma unroll
    for (int it = 0; it < 2; ++it) {
      int gid = it * 512 + t;
      int x = gid >> 4, bx0 = (gid & 15) << 2;
      float4 v = *(const float4*)(gp + (x << 6) + bx0);
      Ts[(bx0 + 0) * 65 + x] = v.x;
      Ts[(bx0 + 1) * 65 + x] = v.y;
      Ts[(bx0 + 2) * 65 + x] = v.z;
      Ts[(bx0 + 3) * 65 + x] = v.w;
    }
  }
  __syncthreads();

  for (int y = y0; y < y1; ++y) {
    // issue register prefetch of plane y+3 (to be written post-compute)
    float4 pf0, pf1;
    bool dopf = (y + 1 < y1);
    if (dopf) {
      const float* gp = P + ((size_t)(((y + 3) << 6) + (y + 3 + k)) << 12);
      pf0 = *(const float4*)(gp + ((t >> 4) << 6) + ((t & 15) << 2));
      int g1 = 512 + t;
      pf1 = *(const float4*)(gp + ((g1 >> 4) << 6) + ((g1 & 15) << 2));
    }
    const float* T0 = T[y % 3];
    const float* T1 = T[(y + 1) % 3];
    const float* T2 = T[(y + 2) % 3];
    float best = -3.0e38f; int bbx = 0;
#pragma unroll
    for (int bb = 0; bb < 8; ++bb) {
      int bx = (w << 3) + bb;
      if (bx > 61) break;           // wave-uniform
      int r0 = bx * 65 + l;
      float s = T0[r0] + T0[r0 + 66] + T0[r0 + 132]
              + T1[r0] + T1[r0 + 66] + T1[r0 + 132]
              + T2[r0] + T2[r0 + 66] + T2[r0 + 132];
      if (s > best) { best = s; bbx = bx; }   // ascending bx: first max
    }
    cv[w][l] = best; ci[w][l] = (unsigned char)bbx;
    __syncthreads();
    if (w == 0) {
      float bv = cv[0][l]; int bj = ci[0][l];
#pragma unroll
      for (int ww = 1; ww < 8; ++ww) {
        float v = cv[ww][l];
        if (v > bv) { bv = v; bj = ci[ww][l]; }  // ascending bx ranges
      }
      if (l <= 61) {
        int o = (ki * 62 + y) * 62 + l;
        pval[o] = bv; pidx[o] = bj;
      }
    }
    if (dopf) {
      float* Ts = T[y % 3];        // retired slot: plane y done after sync
      int x0 = t >> 4, b0x = (t & 15) << 2;
      Ts[(b0x + 0) * 65 + x0] = pf0.x; Ts[(b0x + 1) * 65 + x0] = pf0.y;
      Ts[(b0x + 2) * 65 + x0] = pf0.z; Ts[(b0x + 3) * 65 + x0] = pf0.w;
      int g1 = 512 + t;
      int x1 = g1 >> 4, b1x = (g1 & 15) << 2;
      Ts[(b1x + 0) * 65 + x1] = pf1.x; Ts[(b1x + 1) * 65 + x1] = pf1.y;
      Ts[(b1x + 2) * 65 + x1] = pf1.z; Ts[(b1x + 3) * 65 + x1] = pf1.w;
    }
    __syncthreads();
  }
}

// ---------------------------------------------------------------------------
// Kernel 5: combine diagonal partials over jy (ascending -> first occurrence)
// ---------------------------------------------------------------------------
__global__ __launch_bounds__(256) void combine_kernel(const float* __restrict__ pv0,
                                                      const int* __restrict__ pi0,
                                                      size_t slotElems, int b0,
                                                      float* __restrict__ resv,
                                                      int* __restrict__ residx) {
  int q = blockIdx.x * 256 + threadIdx.x;
  if (q >= NQ) return;
  int slot = blockIdx.y;
  int b = b0 + slot;
  const float* pv = pv0 + (size_t)slot * slotElems;
  const int* pi = pi0 + (size_t)slot * slotElems;
  int y = q / 62, ax = q - y * 62;
  float bv = -3.0e38f; int bj = 0;
  for (int jy = 0; jy < 62; ++jy) {
    int ki = 61 + jy - y;
    int o = (ki * 62 + y) * 62 + ax;
    float v = pv[o];
    if (v > bv) { bv = v; bj = jy * 62 + pi[o]; }
  }
  resv[(size_t)b * NQ + q] = bv;
  residx[(size_t)b * NQ + q] = bj;
}

// ---------------------------------------------------------------------------
// Kernel 6: assemble flow (B,64,64,2), offset (B,9,64,64,2), sim (B,1,64,64).
// ---------------------------------------------------------------------------
__global__ __launch_bounds__(256) void assemble_kernel(const float* __restrict__ res_val,
                                                       const int* __restrict__ res_idx,
                                                       float* __restrict__ out) {
  int gid = blockIdx.x * 256 + threadIdx.x;
  if (gid >= BATCH * HW) return;
  int b = gid >> 12;
  int y = (gid >> 6) & 63;
  int x = gid & 63;

  float* out_flow = out;
  float* out_off = out + (size_t)BATCH * HW * 2;
  float* out_sim = out + (size_t)BATCH * HW * 2 + (size_t)BATCH * 9 * HW * 2;

  auto flow_at = [&](int yy, int xx, float* fx, float* fy) {
    if (yy >= 0 && yy < HH && xx >= 0 && xx < WW) {
      int idx = res_idx[(size_t)b * NQ + yy * WW + xx];
      *fx = (float)(idx % WW - xx);
      *fy = (float)(idx / WW - yy);
    } else {
      *fx = 0.f;
      *fy = 0.f;
    }
  };

  float fx, fy;
  flow_at(y, x, &fx, &fy);
  size_t fo = ((size_t)b * HW + y * W + x) * 2;
  out_flow[fo + 0] = fx;
  out_flow[fo + 1] = fy;

#pragma unroll
  for (int sft = 0; sft < 9; ++sft) {
    int i = sft / 3, j = sft % 3;
    float ox, oy;
    flow_at(y - i, x - j, &ox, &oy);
    size_t o = (((size_t)b * 9 + sft) * HW + y * W + x) * 2;
    out_off[o + 0] = ox;
    out_off[o + 1] = oy;
  }

  float sim = 0.f;
  if (y >= 1 && y <= HH && x >= 1 && x <= WW) {
    float mv = res_val[(size_t)b * NQ + (y - 1) * WW + (x - 1)];
    sim = mv * (1.0f / ((3.0f + 1e-5f) * 3.0f));  // patch norms are exactly 3
  }
  out_sim[(size_t)b * HW + y * W + x] = sim;
}

// ---------------------------------------------------------------------------
extern "C" void kernel_launch(void* const* d_in, const int* in_sizes, int n_in,
                              void* d_out, int out_size, void* d_ws, size_t ws_size,
                              hipStream_t stream) {
  const float* f1 = (const float*)d_in[0];
  const float* f2 = (const float*)d_in[1];
  float* out = (float*)d_out;
  char* ws = (char*)d_ws;

  float* rnorm = (float*)(ws + OFF_RNORM);
  float* resv = (float*)(ws + OFF_RESV);
  int* residx = (int*)(ws + OFF_RESI);
  char* slot0 = ws + OFF_SLOT0;

  // adaptive image-group size from available workspace (deterministic)
  int nslots = 1;
  if (ws_size > OFF_SLOT0 + SLOT_BYTES) {
    size_t n = (ws_size - OFF_SLOT0) / SLOT_BYTES;
    nslots = n >= 8 ? 8 : (int)n;
    if (nslots < 1) nslots = 1;
  }
  size_t slotElems = SLOT_BYTES / 4;

  norm_kernel<<<dim3(BATCH * H, 2), 256, 0, stream>>>(f1, f2, rnorm);

  for (int b0 = 0; b0 < BATCH; b0 += nslots) {
    int g = BATCH - b0 < nslots ? BATCH - b0 : nslots;
    for (int i = 0; i < g; ++i) {
      char* slot = slot0 + (size_t)i * SLOT_BYTES;
      convert_kernel<<<dim3(128, 2), 256, 0, stream>>>(
          f1, f2, rnorm, b0 + i, (u32*)(slot + SP_OP1), (u32*)(slot + SP_OP2));
      pgemm_kernel<<<1024, 256, 0, stream>>>(
          (const u32*)(slot + SP_OP1), (const u32*)(slot + SP_OP2),
          (float*)(slot + SP_P));
    }
    reduce_kernel<<<dim3(NBLK_RED, g), 512, 0, stream>>>(
        (const float*)(slot0 + SP_P), (float*)(slot0 + SP_PVAL),
        (int*)(slot0 + SP_PIDX), slotElems);
    combine_kernel<<<dim3(16, g), 256, 0, stream>>>(
        (const float*)(slot0 + SP_PVAL), (const int*)(slot0 + SP_PIDX),
        slotElems, b0, resv, residx);
  }

  int total = BATCH * HW;
  assemble_kernel<<<(total + 255) / 256, 256, 0, stream>>>(resv, residx, out);
}

// Round 6
// 561.835 us; speedup vs baseline: 19.0648x; 1.1870x over previous
//
#include <hip/hip_runtime.h>

typedef unsigned short u16;
typedef unsigned char u8;
typedef unsigned int u32;
typedef __bf16 bf16x8 __attribute__((ext_vector_type(8)));
typedef float f32x4 __attribute__((ext_vector_type(4)));

constexpr int BATCH = 8;
constexpr int C = 256;
constexpr int H = 64;
constexpr int W = 64;
constexpr int HW = H * W;          // 4096
constexpr int HH = 62, WW = 62;    // valid patch grid
constexpr int NQ = HH * WW;        // 3844
constexpr int SEG = 8;             // y-steps per reduce block
constexpr int NBLK_RED = 536;      // sum over diagonals of ceil(len/SEG)

// ws layout (bytes)
constexpr size_t OFF_RNORM = 0;            // 2*8*4096*4 = 262144
constexpr size_t OFF_RESV = 262144;        // 8*3844*4 = 123008 (pad 123136)
constexpr size_t OFF_RESI = 385280;
constexpr size_t OFF_SLOT0 = 508416;
// per-slot layout. pval8 (reduce value partials, 3844*512*4 = 7,872,512 B)
// OVERLAYS the operand region [0, 8 MB) — operands are dead after pgemm.
// pidx8 (u8 bb indices, 3844*512 = 1,968,128 B) gets its own region after P.
constexpr size_t SP_H1 = 0;                // 4096*256*2 = 2,097,152
constexpr size_t SP_L1 = 2097152;
constexpr size_t SP_H2 = 4194304;
constexpr size_t SP_L2 = 6291456;
constexpr size_t SP_P = 8388608;           // 4096 planes * 16KB = 67,108,864
constexpr size_t SP_PIDX8 = 75497472;      // 1,968,128 B (pad to 2 MB)
constexpr size_t SLOT_BYTES = 77594624;

// async global->LDS, 16B per lane (LDS dest: wave-uniform base + lane*16)
typedef const __attribute__((address_space(1))) unsigned int* gas_ptr;
typedef __attribute__((address_space(3))) unsigned int* las_ptr;
__device__ __forceinline__ void gl16(const void* g, void* l) {
  __builtin_amdgcn_global_load_lds((gas_ptr)g, (las_ptr)l, 16, 0, 0);
}

// prefix over diagonal lengths: len(m) = 62 - |m-61|
__device__ __forceinline__ int pre_of(int ki) {
  if (ki <= 62) return ki * (ki + 1) / 2;
  int r = 123 - ki;                       // 60..1
  return 1953 + 1891 - r * (r + 1) / 2;
}

// ---------------------------------------------------------------------------
// Kernel 1: per-position reciprocal channel-L2 norm. rnorm[tensor][b][pos]
// ---------------------------------------------------------------------------
__global__ __launch_bounds__(256) void norm_kernel(const float* __restrict__ f1,
                                                   const float* __restrict__ f2,
                                                   float* __restrict__ rnorm) {
  int by = blockIdx.x;           // b*H + y
  int tensor = blockIdx.y;
  const float* f = tensor ? f2 : f1;
  int b = by >> 6, y = by & 63;
  int x = threadIdx.x & 63;
  int cq = threadIdx.x >> 6;
  const float* base = f + ((size_t)b * C) * HW + y * W + x;
  float s = 0.f;
  for (int c = cq; c < C; c += 4) {
    float v = base[(size_t)c * HW];
    s = fmaf(v, v, s);
  }
  __shared__ float sm[4][64];
  sm[cq][x] = s;
  __syncthreads();
  if (threadIdx.x < 64) {
    float t = sm[0][x] + sm[1][x] + sm[2][x] + sm[3][x];
    float nrm = fmaxf(sqrtf(t), 1e-12f);
    rnorm[((size_t)tensor * BATCH + b) * HW + y * W + x] = 1.0f / nrm;
  }
}

// ---------------------------------------------------------------------------
// Kernel 2: normalize + hi/lo bf16 split into SEPARATE u16 planes [pos][c].
// (verbatim the R2 transpose body, which passed)
// ---------------------------------------------------------------------------
__global__ __launch_bounds__(256) void convert_kernel(const float* __restrict__ f1,
                                                      const float* __restrict__ f2,
                                                      const float* __restrict__ rnorm,
                                                      int bi,
                                                      u16* __restrict__ hi1, u16* __restrict__ lo1,
                                                      u16* __restrict__ hi2, u16* __restrict__ lo2) {
  int chunk = blockIdx.x;        // 0..127, 32 positions each
  int tensor = blockIdx.y;
  int pos0 = chunk * 32;
  const float* f = (tensor ? f2 : f1) + (size_t)bi * C * HW;
  const float* rn = rnorm + ((size_t)tensor * BATCH + bi) * HW + pos0;
  u16* dh = (tensor ? hi2 : hi1) + (size_t)pos0 * C;
  u16* dl = (tensor ? lo2 : lo1) + (size_t)pos0 * C;

  __shared__ u32 sm[32][257];
  int t = threadIdx.x;
  int px = t & 31, cg = t >> 5;  // cg 0..7
  float r = rn[px];
  for (int kk = 0; kk < 32; ++kk) {
    int c = (cg << 5) + kk;
    float v = f[(size_t)c * HW + pos0 + px] * r;
    __bf16 h = (__bf16)v;        // RNE
    float hf = (float)h;
    __bf16 lo = (__bf16)(v - hf);
    sm[px][c] = ((u32)__builtin_bit_cast(u16, h) << 16) | (u32)__builtin_bit_cast(u16, lo);
  }
  __syncthreads();
  int px2 = t >> 3, seg = t & 7;
  int c0 = seg * 32;
  for (int g8 = 0; g8 < 4; ++g8) {
    u32 hw0, hw1, hw2, hw3, lw0, lw1, lw2, lw3;
    u32 a, b2;
    a = sm[px2][c0 + g8 * 8 + 0]; b2 = sm[px2][c0 + g8 * 8 + 1];
    hw0 = (a >> 16) | (b2 & 0xFFFF0000u); lw0 = (a & 0xFFFFu) | (b2 << 16);
    a = sm[px2][c0 + g8 * 8 + 2]; b2 = sm[px2][c0 + g8 * 8 + 3];
    hw1 = (a >> 16) | (b2 & 0xFFFF0000u); lw1 = (a & 0xFFFFu) | (b2 << 16);
    a = sm[px2][c0 + g8 * 8 + 4]; b2 = sm[px2][c0 + g8 * 8 + 5];
    hw2 = (a >> 16) | (b2 & 0xFFFF0000u); lw2 = (a & 0xFFFFu) | (b2 << 16);
    a = sm[px2][c0 + g8 * 8 + 6]; b2 = sm[px2][c0 + g8 * 8 + 7];
    hw3 = (a >> 16) | (b2 & 0xFFFF0000u); lw3 = (a & 0xFFFFu) | (b2 << 16);
    size_t off = (size_t)px2 * C + c0 + g8 * 8;
    uint4 hv; hv.x = hw0; hv.y = hw1; hv.z = hw2; hv.w = hw3;
    uint4 lv; lv.x = lw0; lv.y = lw1; lv.z = lw2; lv.w = lw3;
    *(uint4*)(dh + off) = hv;
    *(uint4*)(dl + off) = lv;
  }
}

// ---------------------------------------------------------------------------
// Kernel 3: P = f1n^T * f2n (4096x4096x256), split-bf16 3-product MFMA.
// Staging via global_load_lds (16B), XOR swizzle applied on the GLOBAL source
// chunk index (LDS dest linear). Output plane-major.
// ---------------------------------------------------------------------------
__global__ __launch_bounds__(256, 2) void pgemm_kernel(const u16* __restrict__ hi1,
                                                       const u16* __restrict__ lo1,
                                                       const u16* __restrict__ hi2,
                                                       const u16* __restrict__ lo2,
                                                       float* __restrict__ P) {
  int bid = blockIdx.x;
  int swz = (bid & 7) * 128 + (bid >> 3);   // bijective XCD swizzle (1024 blocks)
  int p0 = (swz >> 5) << 7, q0 = (swz & 31) << 7;

  __shared__ __align__(16) char smem[65536];
  char* sAh = smem;
  char* sAl = smem + 16384;
  char* sBh = smem + 32768;
  char* sBl = smem + 49152;

  int t = threadIdx.x;
  int l = t & 63, w = t >> 6, wm = w >> 1, wn = w & 1;
  int lr = l & 15, lh = l >> 4;
  int wv = w;

  const u16* src0 = hi1 + (size_t)p0 * 256;
  const u16* src1 = lo1 + (size_t)p0 * 256;
  const u16* src2 = hi2 + (size_t)q0 * 256;
  const u16* src3 = lo2 + (size_t)q0 * 256;

  f32x4 acc[4][4];
#pragma unroll
  for (int mf = 0; mf < 4; ++mf)
#pragma unroll
    for (int nf = 0; nf < 4; ++nf)
      acc[mf][nf] = (f32x4){0.f, 0.f, 0.f, 0.f};

  for (int kt = 0; kt < 4; ++kt) {
    if (kt) __syncthreads();
#pragma unroll
    for (int qq = 0; qq < 4; ++qq) {
      int q = wv * 4 + qq;
      int row = q * 8 + (l >> 3);
      int cc = l & 7;
      size_t goff = (size_t)row * 256 + kt * 64 + ((cc ^ (row & 7)) << 3);
      gl16(src0 + goff, sAh + q * 1024);
      gl16(src1 + goff, sAl + q * 1024);
      gl16(src2 + goff, sBh + q * 1024);
      gl16(src3 + goff, sBl + q * 1024);
    }
    __syncthreads();
#pragma unroll
    for (int ks = 0; ks < 2; ++ks) {
      bf16x8 ah[4], al[4];
#pragma unroll
      for (int mf = 0; mf < 4; ++mf) {
        int row = wm * 64 + mf * 16 + lr;
        int off = row * 128 + ((((ks * 4 + lh) << 4)) ^ ((row & 7) << 4));
        ah[mf] = *(const bf16x8*)(sAh + off);
        al[mf] = *(const bf16x8*)(sAl + off);
      }
#pragma unroll
      for (int nf = 0; nf < 4; ++nf) {
        int row = wn * 64 + nf * 16 + lr;
        int off = row * 128 + ((((ks * 4 + lh) << 4)) ^ ((row & 7) << 4));
        bf16x8 bh = *(const bf16x8*)(sBh + off);
        bf16x8 bl = *(const bf16x8*)(sBl + off);
#pragma unroll
        for (int mf = 0; mf < 4; ++mf) {
          acc[mf][nf] = __builtin_amdgcn_mfma_f32_16x16x32_bf16(ah[mf], bh, acc[mf][nf], 0, 0, 0);
          acc[mf][nf] = __builtin_amdgcn_mfma_f32_16x16x32_bf16(al[mf], bh, acc[mf][nf], 0, 0, 0);
          acc[mf][nf] = __builtin_amdgcn_mfma_f32_16x16x32_bf16(ah[mf], bl, acc[mf][nf], 0, 0, 0);
        }
      }
    }
  }

  // C/D layout: col = lane&15, row = (lane>>4)*4 + reg
#pragma unroll
  for (int mf = 0; mf < 4; ++mf)
#pragma unroll
    for (int nf = 0; nf < 4; ++nf)
#pragma unroll
      for (int j = 0; j < 4; ++j) {
        int pg = p0 + wm * 64 + mf * 16 + lh * 4 + j;
        int qg = q0 + wn * 64 + nf * 16 + lr;
        size_t addr = (((size_t)((pg >> 6) << 6 | (qg >> 6))) << 12) +
                      ((pg & 63) << 6) + (qg & 63);
        P[addr] = acc[mf][nf][j];
      }
}

// ---------------------------------------------------------------------------
// Kernel 4: streaming diagonal reduce (v3 fixed). Block = (diag k, SEG seg)
// x slot. Ping-pong 2x16KB LDS plane slots via global_load_lds (16B-chunk
// XOR source swizzle, linear LDS dest); per-thread register diagonal
// pre-sums; EXACT per-lane argmax -> pval8 (f32) + pidx8 (u8).
// Race fix: barrier between prologue presum(y0) and issue(y0+2).
// ---------------------------------------------------------------------------
__global__ __launch_bounds__(512) void reduce_kernel(char* __restrict__ slot0,
                                                     size_t slotBytes) {
  int slot = blockIdx.y;
  char* sb = slot0 + (size_t)slot * slotBytes;
  const float* P = (const float*)(sb + SP_P);
  float* pval8 = (float*)sb;               // overlay on operand region
  u8* pidx8 = (u8*)(sb + SP_PIDX8);

  // map blockIdx.x -> (ki, segment)
  int bid = blockIdx.x;
  int ki = 0;
  for (ki = 0; ki < 123; ++ki) {
    int d = ki - 61; if (d < 0) d = -d;
    int ns = (62 - d + SEG - 1) / SEG;
    if (bid < ns) break;
    bid -= ns;
  }
  int k = ki - 61;
  int ystart = k < 0 ? -k : 0;
  int yend = k > 0 ? 61 - k : 61;
  int y0 = ystart + bid * SEG;
  int y1 = y0 + SEG; if (y1 > yend + 1) y1 = yend + 1;
  int sid0 = pre_of(ki) + (y0 - ystart);

  __shared__ __align__(16) float LSLOT[2][4096];

  int t = threadIdx.x;
  int w = t >> 6, l = t & 63;

  // stage plane p (row r=p, col c=p+k) into LSLOT[p&1]
  auto issue = [&](int p) {
    const float* gp = P + ((size_t)((p << 6) + (p + k)) << 12);
#pragma unroll
    for (int qq = 0; qq < 2; ++qq) {
      int q = w * 2 + qq;
      int r = q * 4 + (l >> 4);
      int ccs = l & 15;
      const float* src = gp + r * 64 + ((ccs ^ (r & 15)) << 2);
      gl16(src, (char*)(&LSLOT[p & 1][0]) + q * 1024);
    }
  };

  // diagonal pre-sum of plane p into Dg[8]
  auto presum = [&](int p, float* Dg) {
    const float* S = &LSLOT[p & 1][0];
    float A[12], B[12], Cc[12];
#pragma unroll
    for (int dx = 0; dx < 3; ++dx) {
      int row = l + dx; if (row > 63) row = 63;
      float* dst = dx == 0 ? A : (dx == 1 ? B : Cc);
#pragma unroll
      for (int j3 = 0; j3 < 3; ++j3) {
        int ch = (2 * w + j3) & 15;
        float4 v = *(const float4*)(S + row * 64 + ((ch ^ (row & 15)) << 2));
        dst[j3 * 4 + 0] = v.x; dst[j3 * 4 + 1] = v.y;
        dst[j3 * 4 + 2] = v.z; dst[j3 * 4 + 3] = v.w;
      }
    }
#pragma unroll
    for (int bb = 0; bb < 8; ++bb)
      Dg[bb] = A[bb] + B[bb + 1] + Cc[bb + 2];
  };

  auto candstep = [&](int y, const float* D0, const float* D1, const float* D2) {
    float best = __uint_as_float(0xFF800000u);
    int bbb = 0;
#pragma unroll
    for (int bb = 0; bb < 8; ++bb) {
      float c = D0[bb] + D1[bb] + D2[bb];
      bool valid = (w * 8 + bb) <= 61;
      if (valid && c > best) { best = c; bbb = bb; }  // ascending bb: first max
    }
    size_t o = (size_t)(sid0 + (y - y0)) * 512 + (w << 6) + l;
    pval8[o] = best;
    pidx8[o] = (u8)bbb;
  };

  float DgA[8], DgB[8], DgC[8];

  issue(y0);
  issue(y0 + 1);
  __syncthreads();            // planes y0, y0+1 landed
  presum(y0, DgA);
  __syncthreads();            // RACE FIX: all waves done reading slot y0&1
  issue(y0 + 2);              // now safe to overwrite slot y0&1
  __syncthreads();            // plane y0+2 landed
  presum(y0 + 1, DgB);

  int y = y0;
  while (true) {
    __syncthreads();
    if (y + 1 < y1) issue(y + 3);
    presum(y + 2, DgC);
    candstep(y, DgA, DgB, DgC);
    if (++y >= y1) break;
    __syncthreads();
    if (y + 1 < y1) issue(y + 3);
    presum(y + 2, DgA);
    candstep(y, DgB, DgC, DgA);
    if (++y >= y1) break;
    __syncthreads();
    if (y + 1 < y1) issue(y + 3);
    presum(y + 2, DgB);
    candstep(y, DgC, DgA, DgB);
    if (++y >= y1) break;
  }
}

// ---------------------------------------------------------------------------
// Kernel 5: combine partials over (jy, w) with exact compares; decode bb via
// one pidx8 read. Strict > with ascending (jy, w) preserves first-occurrence.
// ---------------------------------------------------------------------------
__global__ __launch_bounds__(256) void combine_kernel(const char* __restrict__ slot0,
                                                      size_t slotBytes, int b0,
                                                      float* __restrict__ resv,
                                                      int* __restrict__ residx) {
  int q = blockIdx.x * 256 + threadIdx.x;
  if (q >= NQ) return;
  int slot = blockIdx.y;
  int b = b0 + slot;
  const char* sb = slot0 + (size_t)slot * slotBytes;
  const float* pval8 = (const float*)sb;
  const u8* pidx8 = (const u8*)(sb + SP_PIDX8);
  int y = q / 62, ax = q - y * 62;
  float best = __uint_as_float(0xFF800000u);
  int bjy = 0, bw = 0;
  for (int jy = 0; jy < 62; ++jy) {
    int ki = 61 + jy - y;
    int sid = pre_of(ki) + (y < jy ? y : jy);
    const float* p = pval8 + (size_t)sid * 512 + ax;
#pragma unroll
    for (int ww = 0; ww < 8; ++ww) {
      float v = p[ww << 6];
      if (v > best) { best = v; bjy = jy; bw = ww; }
    }
  }
  int kib = 61 + bjy - y;
  int sidb = pre_of(kib) + (y < bjy ? y : bjy);
  int bb = pidx8[(size_t)sidb * 512 + (bw << 6) + ax];
  resv[(size_t)b * NQ + q] = best;
  residx[(size_t)b * NQ + q] = bjy * 62 + bw * 8 + bb;
}

// ---------------------------------------------------------------------------
// Kernel 6: assemble flow (B,64,64,2), offset (B,9,64,64,2), sim (B,1,64,64).
// ---------------------------------------------------------------------------
__global__ __launch_bounds__(256) void assemble_kernel(const float* __restrict__ res_val,
                                                       const int* __restrict__ res_idx,
                                                       float* __restrict__ out) {
  int gid = blockIdx.x * 256 + threadIdx.x;
  if (gid >= BATCH * HW) return;
  int b = gid >> 12;
  int y = (gid >> 6) & 63;
  int x = gid & 63;

  float* out_flow = out;
  float* out_off = out + (size_t)BATCH * HW * 2;
  float* out_sim = out + (size_t)BATCH * HW * 2 + (size_t)BATCH * 9 * HW * 2;

  auto flow_at = [&](int yy, int xx, float* fx, float* fy) {
    if (yy >= 0 && yy < HH && xx >= 0 && xx < WW) {
      int idx = res_idx[(size_t)b * NQ + yy * WW + xx];
      *fx = (float)(idx % WW - xx);
      *fy = (float)(idx / WW - yy);
    } else {
      *fx = 0.f;
      *fy = 0.f;
    }
  };

  float fx, fy;
  flow_at(y, x, &fx, &fy);
  size_t fo = ((size_t)b * HW + y * W + x) * 2;
  out_flow[fo + 0] = fx;
  out_flow[fo + 1] = fy;

#pragma unroll
  for (int sft = 0; sft < 9; ++sft) {
    int i = sft / 3, j = sft % 3;
    float ox, oy;
    flow_at(y - i, x - j, &ox, &oy);
    size_t o = (((size_t)b * 9 + sft) * HW + y * W + x) * 2;
    out_off[o + 0] = ox;
    out_off[o + 1] = oy;
  }

  float sim = 0.f;
  if (y >= 1 && y <= HH && x >= 1 && x <= WW) {
    float mv = res_val[(size_t)b * NQ + (y - 1) * WW + (x - 1)];
    sim = mv * (1.0f / ((3.0f + 1e-5f) * 3.0f));  // patch norms are exactly 3
  }
  out_sim[(size_t)b * HW + y * W + x] = sim;
}

// ---------------------------------------------------------------------------
extern "C" void kernel_launch(void* const* d_in, const int* in_sizes, int n_in,
                              void* d_out, int out_size, void* d_ws, size_t ws_size,
                              hipStream_t stream) {
  const float* f1 = (const float*)d_in[0];
  const float* f2 = (const float*)d_in[1];
  float* out = (float*)d_out;
  char* ws = (char*)d_ws;

  float* rnorm = (float*)(ws + OFF_RNORM);
  float* resv = (float*)(ws + OFF_RESV);
  int* residx = (int*)(ws + OFF_RESI);
  char* slot0 = ws + OFF_SLOT0;

  // adaptive image-group size from available workspace (deterministic)
  int nslots = 1;
  if (ws_size > OFF_SLOT0 + SLOT_BYTES) {
    size_t n = (ws_size - OFF_SLOT0) / SLOT_BYTES;
    nslots = n >= 8 ? 8 : (int)n;
    if (nslots < 1) nslots = 1;
  }

  norm_kernel<<<dim3(BATCH * H, 2), 256, 0, stream>>>(f1, f2, rnorm);

  for (int b0 = 0; b0 < BATCH; b0 += nslots) {
    int g = BATCH - b0 < nslots ? BATCH - b0 : nslots;
    for (int i = 0; i < g; ++i) {
      char* slot = slot0 + (size_t)i * SLOT_BYTES;
      convert_kernel<<<dim3(128, 2), 256, 0, stream>>>(
          f1, f2, rnorm, b0 + i,
          (u16*)(slot + SP_H1), (u16*)(slot + SP_L1),
          (u16*)(slot + SP_H2), (u16*)(slot + SP_L2));
      pgemm_kernel<<<1024, 256, 0, stream>>>(
          (const u16*)(slot + SP_H1), (const u16*)(slot + SP_L1),
          (const u16*)(slot + SP_H2), (const u16*)(slot + SP_L2),
          (float*)(slot + SP_P));
    }
    reduce_kernel<<<dim3(NBLK_RED, g), 512, 0, stream>>>(slot0, SLOT_BYTES);
    combine_kernel<<<dim3(16, g), 256, 0, stream>>>(slot0, SLOT_BYTES, b0,
                                                    resv, residx);
  }

  int total = BATCH * HW;
  assemble_kernel<<<(total + 255) / 256, 256, 0, stream>>>(resv, residx, out);
}